// Round 18
// baseline (81.212 us; speedup 1.0000x reference)
//
#include <hip/hip_runtime.h>

#define NN 8
#define MM 8
#define NH1 64
#define NH2 32

#define FOR8(OP) OP(0) OP(1) OP(2) OP(3) OP(4) OP(5) OP(6) OP(7)

#define REP16(M) M(0) M(1) M(2) M(3) M(4) M(5) M(6) M(7) \
                 M(8) M(9) M(10) M(11) M(12) M(13) M(14) M(15)
#define REP64(M) M(0) M(1) M(2) M(3) M(4) M(5) M(6) M(7) \
                 M(8) M(9) M(10) M(11) M(12) M(13) M(14) M(15) \
                 M(16) M(17) M(18) M(19) M(20) M(21) M(22) M(23) \
                 M(24) M(25) M(26) M(27) M(28) M(29) M(30) M(31) \
                 M(32) M(33) M(34) M(35) M(36) M(37) M(38) M(39) \
                 M(40) M(41) M(42) M(43) M(44) M(45) M(46) M(47) \
                 M(48) M(49) M(50) M(51) M(52) M(53) M(54) M(55) \
                 M(56) M(57) M(58) M(59) M(60) M(61) M(62) M(63)

typedef float v2f  __attribute__((ext_vector_type(2)));
typedef float sf16 __attribute__((ext_vector_type(16)));

// ---- scalar-pipe streaming: depth-1, lgkmcnt(0)-only (SMEM returns may be
// out-of-order -> counted waits unsound; R16). All call sites are stamped
// with LITERAL offsets so "n" is always an ICE (R17 lesson). ----
#define S_ISSUE2(d0, d1, base, imm)                                    \
    asm volatile("s_load_dwordx16 %0, %2, %c3\n\t"                     \
                 "s_load_dwordx16 %1, %2, %c4"                         \
                 : "=&s"(d0), "=&s"(d1)                                \
                 : "s"(base), "n"(imm), "n"((imm) + 64))

#define S_ISSUE1(d0, base, imm)                                        \
    asm volatile("s_load_dwordx16 %0, %1, %c2"                         \
                 : "=&s"(d0) : "s"(base), "n"(imm))

#define S_WAIT2(d0, d1)                                                \
    asm volatile("s_waitcnt lgkmcnt(0)" : "+s"(d0), "+s"(d1))

#define S_WAIT1(d0)                                                    \
    asm volatile("s_waitcnt lgkmcnt(0)" : "+s"(d0))

// acc += w * xi, packed f32; w folded from SGPR pair; acc pinned in VGPRs.
#define PKFMA(acc, w, xi)                                              \
    asm("v_pk_fma_f32 %0, %1, %2, %0" : "+v"(acc) : "s"(w), "v"(xi))

struct U8 { float u0, u1, u2, u3, u4, u5, u6, u7; };

// ---- QP: exact piecewise-linear root isolation + frozen-active-set KKT ----
#define CTERM(j) { float u = fmaf(lam, g##j, -p##j);                   \
                   u = fminf(fmaxf(u, -1.0f), 1.0f);                   \
                   c = fmaf(g##j, u, c); }
#define BP(j) {                                                        \
        const float rg = __builtin_amdgcn_rcpf(g##j);                  \
        const float bpa = (p##j - 1.0f) * rg;                          \
        const float bpb = (p##j + 1.0f) * rg;                          \
        const float ca = c_of(bpa);                                    \
        const float cb = c_of(bpb);                                    \
        lamL = (bpa > 0.0f && ca <  0.0f && bpa > lamL) ? bpa : lamL;  \
        lamR = (bpa > 0.0f && ca >= 0.0f && bpa < lamR) ? bpa : lamR;  \
        lamL = (bpb > 0.0f && cb <  0.0f && bpb > lamL) ? bpb : lamL;  \
        lamR = (bpb > 0.0f && cb >= 0.0f && bpb < lamR) ? bpb : lamR;  \
    }
#define ASET(j)                                                        \
    const float ur##j = fmaf(lam_t, g##j, -p##j);                      \
    const bool lo##j = (ur##j <= -1.0f);                               \
    const bool hi##j = (ur##j >=  1.0f);                               \
    denom += (!(lo##j || hi##j)) ? g##j * g##j : 0.0f;                 \
    num   += lo##j ? -g##j : (hi##j ? g##j : -g##j * p##j);
#define UOUT(j) const float uo##j =                                    \
    lo##j ? -1.0f : (hi##j ? 1.0f : fmaf(lam, g##j, -p##j));

__device__ __forceinline__ U8 qp_solve(
    float c0,
    float p0, float p1, float p2, float p3,
    float p4, float p5, float p6, float p7,
    float g0, float g1, float g2, float g3,
    float g4, float g5, float g6, float g7)
{
    auto c_of = [&](float lam) -> float {
        float c = c0;
        FOR8(CTERM)
        return c;
    };
    const bool viol = (c_of(0.0f) < 0.0f);
    const float BIGR = 3.0e38f;
    float lamL = 0.0f, lamR = BIGR;
    FOR8(BP)
    const bool infeas = (lamR == BIGR);
    float lam_t = infeas ? 1.099511627776e12f : 0.5f * (lamL + lamR);
    lam_t = viol ? lam_t : 0.0f;
    float denom = 0.0f, num = c0;
    FOR8(ASET)
    const float lam = viol ? (-num / (denom + 1e-12f)) : 0.0f;
    FOR8(UOUT)
    return U8{uo0, uo1, uo2, uo3, uo4, uo5, uo6, uo7};
}

// =====================================================================
// 2 rows/thread on the R12 scalar-stream skeleton. Each 128B weight
// batch feeds 32 pk-FMA (both rows) -> issue-to-wait distance ~128cy
// covers the ~150cy SMEM latency at depth-1. Per-row chains bitwise-
// identical to R12. All iterations preprocessor-stamped (literal
// indices -> ICE asm offsets + static register indexing).
// =====================================================================
__device__ __forceinline__ void compute_pair(
    int rA, int rB, bool vB,
    const float* __restrict__ x_g,
    const float* __restrict__ W1,  const float* __restrict__ b1,
    const float* __restrict__ W21, const float* __restrict__ b21,
    const float* __restrict__ W22, const float* __restrict__ b22,
    const float* __restrict__ W31, const float* __restrict__ b31,
    const float* __restrict__ W32, const float* __restrict__ b32,
    const float* __restrict__ Amat, const float* __restrict__ Gmat,
    const float* __restrict__ mean, const float* __restrict__ std_,
    float* __restrict__ out)
{
    const int rBl = vB ? rB : rA;

    // ---- load x for both rows ----
    float xA[NN], xB[NN];
    {
        const float4* xva = reinterpret_cast<const float4*>(x_g + (size_t)rA * NN);
        const float4* xvb = reinterpret_cast<const float4*>(x_g + (size_t)rBl * NN);
        float4 a0 = xva[0], a1 = xva[1], c0v = xvb[0], c1v = xvb[1];
        xA[0]=a0.x; xA[1]=a0.y; xA[2]=a0.z; xA[3]=a0.w;
        xA[4]=a1.x; xA[5]=a1.y; xA[6]=a1.z; xA[7]=a1.w;
        xB[0]=c0v.x; xB[1]=c0v.y; xB[2]=c0v.z; xB[3]=c0v.w;
        xB[4]=c1v.x; xB[5]=c1v.y; xB[6]=c1v.z; xB[7]=c1v.w;
    }

    // ---- un-normalized state (shared mean/std) ----
    float x0A[NN], x0B[NN];
#pragma unroll
    for (int i = 0; i < NN; ++i) {
        const float sd = std_[i], mn = mean[i];
        x0A[i] = fmaf(xA[i], sd, mn);
        x0B[i] = fmaf(xB[i], sd, mn);
    }

    // =====================================================================
    // Layer 1: 16 stamped units of 128B; 32 pk-FMA each (16 per row).
    // =====================================================================
    v2f hvA[NH1 / 2], hvB[NH1 / 2];
#pragma unroll
    for (int j2 = 0; j2 < NH1 / 2; ++j2) {
        const v2f b = *(const v2f*)(b1 + 2 * j2);
        hvA[j2] = b; hvB[j2] = b;
    }

#define L1CMP(Ra, Rb, hh)                                                      \
    _Pragma("unroll")                                                          \
    for (int j2 = 0; j2 < 8; ++j2) { const v2f w = { Ra[2*j2], Ra[2*j2+1] };   \
        PKFMA(hvA[(hh)*16 + j2], w, xiA); PKFMA(hvB[(hh)*16 + j2], w, xiB); }  \
    _Pragma("unroll")                                                          \
    for (int j2 = 0; j2 < 8; ++j2) { const v2f w = { Rb[2*j2], Rb[2*j2+1] };   \
        PKFMA(hvA[(hh)*16 + 8 + j2], w, xiA); PKFMA(hvB[(hh)*16 + 8 + j2], w, xiB); }

#define L1U(u) {                                                               \
        const v2f xiA = { xA[(u) >> 1], xA[(u) >> 1] };                        \
        const v2f xiB = { xB[(u) >> 1], xB[(u) >> 1] };                        \
        if (((u) & 1) == 0) {                                                  \
            if ((u) + 1 < 16) S_ISSUE2(tB0, tB1, W1, ((u) + 1) * 128);         \
            L1CMP(tA0, tA1, ((u) & 1))                                         \
            if ((u) + 1 < 16) S_WAIT2(tB0, tB1);                               \
        } else {                                                               \
            if ((u) + 1 < 16) S_ISSUE2(tA0, tA1, W1, ((u) + 1) * 128);         \
            L1CMP(tB0, tB1, ((u) & 1))                                         \
            if ((u) + 1 < 16) S_WAIT2(tA0, tA1);                               \
        } }

    {
        sf16 tA0, tA1, tB0, tB1;
        S_ISSUE2(tA0, tA1, W1, 0);
        S_WAIT2(tA0, tA1);
        REP16(L1U)
    }
    {
        const v2f zero2 = { 0.0f, 0.0f };
#pragma unroll
        for (int j2 = 0; j2 < NH1 / 2; ++j2) {
            hvA[j2] = __builtin_elementwise_max(hvA[j2], zero2);
            hvB[j2] = __builtin_elementwise_max(hvB[j2], zero2);
        }
    }

    // =====================================================================
    // Layer-2 passes: 64 stamped units of 128B; 32 pk-FMA each.
    // =====================================================================
#define L2CMP(Qa, Qb)                                                          \
    _Pragma("unroll")                                                          \
    for (int j2 = 0; j2 < 8; ++j2) { const v2f w = { Qa[2*j2], Qa[2*j2+1] };   \
        PKFMA(accA_[j2], w, hbA); PKFMA(accB_[j2], w, hbB); }                  \
    _Pragma("unroll")                                                          \
    for (int j2 = 0; j2 < 8; ++j2) { const v2f w = { Qb[2*j2], Qb[2*j2+1] };   \
        PKFMA(accA_[8 + j2], w, hbA); PKFMA(accB_[8 + j2], w, hbB); }

#define L2U(k) {                                                               \
        const v2f hbA = ((k) & 1) ? hvA[(k) >> 1].yy : hvA[(k) >> 1].xx;       \
        const v2f hbB = ((k) & 1) ? hvB[(k) >> 1].yy : hvB[(k) >> 1].xx;       \
        if (((k) & 1) == 0) {                                                  \
            if ((k) + 1 < NH1) S_ISSUE2(qB0, qB1, wb_, ((k) + 1) * 128);       \
            L2CMP(qA0, qA1)                                                    \
            if ((k) + 1 < NH1) S_WAIT2(qB0, qB1);                              \
        } else {                                                               \
            if ((k) + 1 < NH1) S_ISSUE2(qA0, qA1, wb_, ((k) + 1) * 128);       \
            L2CMP(qB0, qB1)                                                    \
            if ((k) + 1 < NH1) S_WAIT2(qA0, qA1);                              \
        } }

#define L2PASS(ACCA, ACCB, WBASE) {                                            \
        v2f (&accA_)[NH2 / 2] = ACCA;                                          \
        v2f (&accB_)[NH2 / 2] = ACCB;                                          \
        const float* wb_ = WBASE;                                              \
        sf16 qA0, qA1, qB0, qB1;                                               \
        S_ISSUE2(qA0, qA1, wb_, 0);                                            \
        S_WAIT2(qA0, qA1);                                                     \
        REP64(L2U)                                                             \
    }

    // ---- a22 pass (alpha path, f32 exact) ----
    v2f a22A[NH2 / 2], a22B[NH2 / 2];
#pragma unroll
    for (int j2 = 0; j2 < NH2 / 2; ++j2) {
        const v2f b = *(const v2f*)(b22 + 2 * j2);
        a22A[j2] = b; a22B[j2] = b;
    }
    L2PASS(a22A, a22B, W22)

    // ---- alpha-head (f32 exact, k ascending) ----
    sf16 wA0, wA1;
    S_ISSUE2(wA0, wA1, W32, 0);
    {
        const v2f zero2 = { 0.0f, 0.0f };
#pragma unroll
        for (int j2 = 0; j2 < NH2 / 2; ++j2) {
            a22A[j2] = __builtin_elementwise_max(a22A[j2], zero2);
            a22B[j2] = __builtin_elementwise_max(a22B[j2], zero2);
        }
    }
    S_WAIT2(wA0, wA1);
    float sA = b32[0];
    float sB = sA;
#pragma unroll
    for (int k = 0; k < 16; ++k) {
        const float w = wA0[k];
        sA = fmaf((k & 1) ? a22A[k >> 1].y : a22A[k >> 1].x, w, sA);
        sB = fmaf((k & 1) ? a22B[k >> 1].y : a22B[k >> 1].x, w, sB);
    }
#pragma unroll
    for (int k = 16; k < 32; ++k) {
        const float w = wA1[k - 16];
        sA = fmaf((k & 1) ? a22A[k >> 1].y : a22A[k >> 1].x, w, sA);
        sB = fmaf((k & 1) ? a22B[k >> 1].y : a22B[k >> 1].x, w, sB);
    }
    const float alphaA = 4.0f / (1.0f + __expf(-sA));
    const float alphaB = 4.0f / (1.0f + __expf(-sB));
    // a22 dead here.

    // ---- a21 pass (p path, f32) ----
    v2f a21A[NH2 / 2], a21B[NH2 / 2];
#pragma unroll
    for (int j2 = 0; j2 < NH2 / 2; ++j2) {
        const v2f b = *(const v2f*)(b21 + 2 * j2);
        a21A[j2] = b; a21B[j2] = b;
    }
    L2PASS(a21A, a21B, W21)

    {
        const v2f zero2 = { 0.0f, 0.0f };
#pragma unroll
        for (int j2 = 0; j2 < NH2 / 2; ++j2) {
            a21A[j2] = __builtin_elementwise_max(a21A[j2], zero2);
            a21B[j2] = __builtin_elementwise_max(a21B[j2], zero2);
        }
    }
    // hv dead here.

    // ---- p-head: 16 stamped units of 64B; 16 pk-FMA each ----
    v2f pvA[MM / 2], pvB[MM / 2];
#pragma unroll
    for (int j2 = 0; j2 < MM / 2; ++j2) {
        const v2f b = *(const v2f*)(b31 + 2 * j2);
        pvA[j2] = b; pvB[j2] = b;
    }

#define PCMPU(P, k2) {                                                         \
        const v2f haA = a21A[(k2)].xx, h2A = a21A[(k2)].yy;                    \
        const v2f haB = a21B[(k2)].xx, h2B = a21B[(k2)].yy;                    \
        _Pragma("unroll") for (int j2 = 0; j2 < 4; ++j2) {                     \
            const v2f w = { P[2*j2], P[2*j2+1] };                              \
            PKFMA(pvA[j2], w, haA); PKFMA(pvB[j2], w, haB); }                  \
        _Pragma("unroll") for (int j2 = 0; j2 < 4; ++j2) {                     \
            const v2f w = { P[8+2*j2], P[8+2*j2+1] };                          \
            PKFMA(pvA[j2], w, h2A); PKFMA(pvB[j2], w, h2B); } }

#define PU(k2) {                                                               \
        if (((k2) & 1) == 0) {                                                 \
            if ((k2) + 1 < 16) S_ISSUE1(pB, W31, ((k2) + 1) * 64);             \
            PCMPU(pA, (k2))                                                    \
            if ((k2) + 1 < 16) S_WAIT1(pB);                                    \
        } else {                                                               \
            if ((k2) + 1 < 16) S_ISSUE1(pA, W31, ((k2) + 1) * 64);             \
            PCMPU(pB, (k2))                                                    \
            if ((k2) + 1 < 16) S_WAIT1(pA);                                    \
        } }

    {
        sf16 pA, pB;
        S_ISSUE1(pA, W31, 0);
        S_WAIT1(pA);
        REP16(PU)
    }

    // ---- barrier terms (shared A/G loads, both rows) ----
    float hxA = 16.0f, hxB = 16.0f;
#pragma unroll
    for (int i = 0; i < NN; ++i) {
        hxA = fmaf(-x0A[i], x0A[i], hxA);
        hxB = fmaf(-x0B[i], x0B[i], hxB);
    }
    float dhA[NN], dhB[NN];
#pragma unroll
    for (int i = 0; i < NN; ++i) { dhA[i] = -2.0f * x0A[i]; dhB[i] = -2.0f * x0B[i]; }

    float LfA = 0.0f, LfB = 0.0f;
#pragma unroll
    for (int i = 0; i < NN; ++i) {
        float fxA = 0.0f, fxB = 0.0f;
#pragma unroll
        for (int k = 0; k < NN; ++k) {
            const float a = Amat[i * NN + k];
            fxA = fmaf(a, x0A[k], fxA);
            fxB = fmaf(a, x0B[k], fxB);
        }
        LfA = fmaf(dhA[i], fxA, LfA);
        LfB = fmaf(dhB[i], fxB, LfB);
    }

#define GDECL(j) float gA##j = 0.0f, gB##j = 0.0f;
    FOR8(GDECL)
#undef GDECL
#pragma unroll
    for (int i = 0; i < NN; ++i) {
        const float da = dhA[i], db = dhB[i];
#define GACC(j) { const float w = Gmat[i * MM + j];                    \
                  gA##j = fmaf(da, w, gA##j);                          \
                  gB##j = fmaf(db, w, gB##j); }
        FOR8(GACC)
#undef GACC
    }

    const float c0A = fmaf(alphaA, hxA, LfA);
    const float c0B = fmaf(alphaB, hxB, LfB);

    // ---- QP per row (exact; all-scalar) ----
    const U8 uA = qp_solve(c0A,
        pvA[0].x, pvA[0].y, pvA[1].x, pvA[1].y,
        pvA[2].x, pvA[2].y, pvA[3].x, pvA[3].y,
        gA0, gA1, gA2, gA3, gA4, gA5, gA6, gA7);
    const U8 uB = qp_solve(c0B,
        pvB[0].x, pvB[0].y, pvB[1].x, pvB[1].y,
        pvB[2].x, pvB[2].y, pvB[3].x, pvB[3].y,
        gB0, gB1, gB2, gB3, gB4, gB5, gB6, gB7);

    // ---- stores ----
    float4* ovA = reinterpret_cast<float4*>(out + (size_t)rA * MM);
    ovA[0] = make_float4(uA.u0, uA.u1, uA.u2, uA.u3);
    ovA[1] = make_float4(uA.u4, uA.u5, uA.u6, uA.u7);
    if (vB) {
        float4* ovB = reinterpret_cast<float4*>(out + (size_t)rB * MM);
        ovB[0] = make_float4(uB.u0, uB.u1, uB.u2, uB.u3);
        ovB[1] = make_float4(uB.u4, uB.u5, uB.u6, uB.u7);
    }
}

#define ARGS_DECL                                                       \
    const float* __restrict__ x_g,                                      \
    const float* __restrict__ W1,  const float* __restrict__ b1,        \
    const float* __restrict__ W21, const float* __restrict__ b21,       \
    const float* __restrict__ W22, const float* __restrict__ b22,       \
    const float* __restrict__ W31, const float* __restrict__ b31,       \
    const float* __restrict__ W32, const float* __restrict__ b32,       \
    const float* __restrict__ Amat, const float* __restrict__ Gmat,     \
    const float* __restrict__ mean, const float* __restrict__ std_,    \
    float* __restrict__ out
#define ARGS_PASS x_g, W1, b1, W21, b21, W22, b22, W31, b31, W32, b32, \
                  Amat, Gmat, mean, std_, out

// Clean kernel: B % 512 == 0 -> uniform control flow, both rows valid.
__global__ __launch_bounds__(256, 2) void barrier_policy_clean(ARGS_DECL)
{
    const int rA = blockIdx.x * 512 + threadIdx.x;
    compute_pair(rA, rA + 256, true, ARGS_PASS);
}

// Guarded fallback for arbitrary B.
__global__ __launch_bounds__(256, 2) void barrier_policy_guard(ARGS_DECL, int B)
{
    const int rA = blockIdx.x * 512 + threadIdx.x;
    if (rA >= B) return;
    const int rB = rA + 256;
    compute_pair(rA, rB, rB < B, ARGS_PASS);
}

extern "C" void kernel_launch(void* const* d_in, const int* in_sizes, int n_in,
                              void* d_out, int out_size, void* d_ws, size_t ws_size,
                              hipStream_t stream) {
    const float* x    = (const float*)d_in[0];
    const float* W1   = (const float*)d_in[1];
    const float* b1   = (const float*)d_in[2];
    const float* W21  = (const float*)d_in[3];
    const float* b21  = (const float*)d_in[4];
    const float* W22  = (const float*)d_in[5];
    const float* b22  = (const float*)d_in[6];
    const float* W31  = (const float*)d_in[7];
    const float* b31  = (const float*)d_in[8];
    const float* W32  = (const float*)d_in[9];
    const float* b32  = (const float*)d_in[10];
    const float* Amat = (const float*)d_in[11];
    const float* Gmat = (const float*)d_in[12];
    const float* mean = (const float*)d_in[13];
    const float* std_ = (const float*)d_in[14];
    float* out = (float*)d_out;

    const int B = in_sizes[0] / NN;
    if (B % 512 == 0) {
        barrier_policy_clean<<<B / 512, 256, 0, stream>>>(
            x, W1, b1, W21, b21, W22, b22, W31, b31, W32, b32,
            Amat, Gmat, mean, std_, out);
    } else {
        barrier_policy_guard<<<(B + 511) / 512, 256, 0, stream>>>(
            x, W1, b1, W21, b21, W22, b22, W31, b31, W32, b32,
            Amat, Gmat, mean, std_, out, B);
    }
}

// Round 19
// 43.594 us; speedup vs baseline: 1.8629x; 1.8629x over previous
//
#include <hip/hip_runtime.h>

#define NN 8
#define MM 8
#define NH1 64
#define NH2 32

#define FOR8(OP) OP(0) OP(1) OP(2) OP(3) OP(4) OP(5) OP(6) OP(7)

typedef float v2f  __attribute__((ext_vector_type(2)));
typedef float sf16 __attribute__((ext_vector_type(16)));

// ---- scalar-pipe streaming: split ISSUE (no wait) / WAIT (tied to data) ----
// ISSUE: two s_load_dwordx16 (128B) at base + byte-imm. No wait -> loads fly
// under the following VALU block. volatile pins placement.
#define S_ISSUE2(d0, d1, base, imm)                                    \
    asm volatile("s_load_dwordx16 %0, %2, %c3\n\t"                     \
                 "s_load_dwordx16 %1, %2, %c4"                         \
                 : "=&s"(d0), "=&s"(d1)                                \
                 : "s"(base), "n"(imm), "n"((imm) + 64))

#define S_ISSUE1(d0, base, imm)                                        \
    asm volatile("s_load_dwordx16 %0, %1, %c2"                         \
                 : "=&s"(d0) : "s"(base), "n"(imm))

// WAIT: lgkmcnt(0) with the buffers as in/out operands -> consumers of the
// buffer are dataflow-ordered AFTER the wait (rule-#18-safe, no sched hoist).
#define S_WAIT2(d0, d1)                                                \
    asm volatile("s_waitcnt lgkmcnt(0)" : "+s"(d0), "+s"(d1))

#define S_WAIT1(d0)                                                    \
    asm volatile("s_waitcnt lgkmcnt(0)" : "+s"(d0))

// acc += w * xi, packed f32. w is the ONE scalar (SGPR-pair) operand folded
// directly into VOP3P src0 -> zero v_mov staging.
#define PKFMA(acc, w, xi)                                              \
    asm("v_pk_fma_f32 %0, %1, %2, %0" : "+v"(acc) : "s"(w), "v"(xi))

__device__ __forceinline__ void compute_row(
    int row,
    const float* __restrict__ x_g,
    const float* __restrict__ W1,  const float* __restrict__ b1,
    const float* __restrict__ W21, const float* __restrict__ b21,
    const float* __restrict__ W22, const float* __restrict__ b22,
    const float* __restrict__ W31, const float* __restrict__ b31,
    const float* __restrict__ W32, const float* __restrict__ b32,
    const float* __restrict__ Amat, const float* __restrict__ Gmat,
    const float* __restrict__ mean, const float* __restrict__ std_,
    float* __restrict__ out)
{
    // ---- load x (per-lane, vectorized) ----
    float x[NN];
    {
        const float4* xv = reinterpret_cast<const float4*>(x_g + (size_t)row * NN);
        float4 a0 = xv[0], a1 = xv[1];
        x[0] = a0.x; x[1] = a0.y; x[2] = a0.z; x[3] = a0.w;
        x[4] = a1.x; x[5] = a1.y; x[6] = a1.z; x[7] = a1.w;
    }

    // ---- un-normalized state ----
    float x0[NN];
    {
        const float4 sd0 = ((const float4*)std_)[0], sd1 = ((const float4*)std_)[1];
        const float4 mn0 = ((const float4*)mean)[0], mn1 = ((const float4*)mean)[1];
        x0[0] = fmaf(x[0], sd0.x, mn0.x); x0[1] = fmaf(x[1], sd0.y, mn0.y);
        x0[2] = fmaf(x[2], sd0.z, mn0.z); x0[3] = fmaf(x[3], sd0.w, mn0.w);
        x0[4] = fmaf(x[4], sd1.x, mn1.x); x0[5] = fmaf(x[5], sd1.y, mn1.y);
        x0[6] = fmaf(x[6], sd1.z, mn1.z); x0[7] = fmaf(x[7], sd1.w, mn1.w);
    }

    // =====================================================================
    // Layer 1: 16 units of 128B (unit u: row i = u>>1, half h = u&1).
    // Depth-1 pipelined scalar stream; chain order per hv[j] = i ascending
    // (identical to round 6/10).
    // =====================================================================
    v2f hv[NH1 / 2];
#pragma unroll
    for (int j2 = 0; j2 < NH1 / 2; ++j2) hv[j2] = *(const v2f*)(b1 + 2 * j2);

    {
        sf16 rA0, rA1, rB0, rB1;
        S_ISSUE2(rA0, rA1, W1, 0);
        S_WAIT2(rA0, rA1);
#pragma unroll
        for (int u = 0; u < 16; ++u) {
            const int i = u >> 1, hh = u & 1;
            const v2f xi = { x[i], x[i] };
            if ((u & 1) == 0) {
                if (u + 1 < 16) S_ISSUE2(rB0, rB1, W1, (u + 1) * 128);
#pragma unroll
                for (int j2 = 0; j2 < 8; ++j2) { const v2f w = { rA0[2*j2], rA0[2*j2+1] }; PKFMA(hv[hh*16 + j2], w, xi); }
#pragma unroll
                for (int j2 = 0; j2 < 8; ++j2) { const v2f w = { rA1[2*j2], rA1[2*j2+1] }; PKFMA(hv[hh*16 + 8 + j2], w, xi); }
                if (u + 1 < 16) S_WAIT2(rB0, rB1);
            } else {
                if (u + 1 < 16) S_ISSUE2(rA0, rA1, W1, (u + 1) * 128);
#pragma unroll
                for (int j2 = 0; j2 < 8; ++j2) { const v2f w = { rB0[2*j2], rB0[2*j2+1] }; PKFMA(hv[hh*16 + j2], w, xi); }
#pragma unroll
                for (int j2 = 0; j2 < 8; ++j2) { const v2f w = { rB1[2*j2], rB1[2*j2+1] }; PKFMA(hv[hh*16 + 8 + j2], w, xi); }
                if (u + 1 < 16) S_WAIT2(rA0, rA1);
            }
        }
    }
    {
        const v2f zero2 = { 0.0f, 0.0f };
#pragma unroll
        for (int j2 = 0; j2 < NH1 / 2; ++j2) hv[j2] = __builtin_elementwise_max(hv[j2], zero2);
    }

    // =====================================================================
    // Layer 2, two pipelined passes (a21 over W21, then a22 over W22).
    // Chain per accumulator = k ascending -> bitwise-identical to round 6.
    // =====================================================================
    v2f a21[NH2 / 2], a22[NH2 / 2];
#pragma unroll
    for (int j2 = 0; j2 < NH2 / 2; ++j2) {
        a21[j2] = *(const v2f*)(b21 + 2 * j2);
        a22[j2] = *(const v2f*)(b22 + 2 * j2);
    }

#define L2PASS(ACC, WBASE)                                                     \
    {                                                                          \
        sf16 qA0, qA1, qB0, qB1;                                               \
        S_ISSUE2(qA0, qA1, WBASE, 0);                                          \
        S_WAIT2(qA0, qA1);                                                     \
        _Pragma("unroll")                                                      \
        for (int k = 0; k < NH1; ++k) {                                        \
            const v2f hb = (k & 1) ? hv[k >> 1].yy : hv[k >> 1].xx;            \
            if ((k & 1) == 0) {                                                \
                if (k + 1 < NH1) S_ISSUE2(qB0, qB1, WBASE, (k + 1) * 128);     \
                _Pragma("unroll")                                              \
                for (int j2 = 0; j2 < 8; ++j2) { const v2f w = { qA0[2*j2], qA0[2*j2+1] }; PKFMA(ACC[j2], w, hb); } \
                _Pragma("unroll")                                              \
                for (int j2 = 0; j2 < 8; ++j2) { const v2f w = { qA1[2*j2], qA1[2*j2+1] }; PKFMA(ACC[8 + j2], w, hb); } \
                if (k + 1 < NH1) S_WAIT2(qB0, qB1);                            \
            } else {                                                           \
                if (k + 1 < NH1) S_ISSUE2(qA0, qA1, WBASE, (k + 1) * 128);     \
                _Pragma("unroll")                                              \
                for (int j2 = 0; j2 < 8; ++j2) { const v2f w = { qB0[2*j2], qB0[2*j2+1] }; PKFMA(ACC[j2], w, hb); } \
                _Pragma("unroll")                                              \
                for (int j2 = 0; j2 < 8; ++j2) { const v2f w = { qB1[2*j2], qB1[2*j2+1] }; PKFMA(ACC[8 + j2], w, hb); } \
                if (k + 1 < NH1) S_WAIT2(qA0, qA1);                            \
            }                                                                  \
        }                                                                      \
    }

    L2PASS(a21, W21)
    L2PASS(a22, W22)
#undef L2PASS

    {
        const v2f zero2 = { 0.0f, 0.0f };
#pragma unroll
        for (int j2 = 0; j2 < NH2 / 2; ++j2) {
            a21[j2] = __builtin_elementwise_max(a21[j2], zero2);
            a22[j2] = __builtin_elementwise_max(a22[j2], zero2);
        }
    }

    // ---- alpha-head weights: issue early, consumed after p-head ----
    sf16 wA0, wA1;
    S_ISSUE2(wA0, wA1, W32, 0);

    // ---- p-head: 16 pipelined units of one x16 (rows 2k2, 2k2+1) ----
    v2f pv[MM / 2];
#pragma unroll
    for (int j2 = 0; j2 < MM / 2; ++j2) pv[j2] = *(const v2f*)(b31 + 2 * j2);
    {
        sf16 pA, pB;
        S_ISSUE1(pA, W31, 0);
        S_WAIT1(pA);
#pragma unroll
        for (int k2 = 0; k2 < NH2 / 2; ++k2) {
            const v2f ha = a21[k2].xx, hb2 = a21[k2].yy;
            if ((k2 & 1) == 0) {
                if (k2 + 1 < 16) S_ISSUE1(pB, W31, (k2 + 1) * 64);
#pragma unroll
                for (int j2 = 0; j2 < 4; ++j2) { const v2f w = { pA[2*j2], pA[2*j2+1] }; PKFMA(pv[j2], w, ha); }
#pragma unroll
                for (int j2 = 0; j2 < 4; ++j2) { const v2f w = { pA[8 + 2*j2], pA[8 + 2*j2+1] }; PKFMA(pv[j2], w, hb2); }
                if (k2 + 1 < 16) S_WAIT1(pB);
            } else {
                if (k2 + 1 < 16) S_ISSUE1(pA, W31, (k2 + 1) * 64);
#pragma unroll
                for (int j2 = 0; j2 < 4; ++j2) { const v2f w = { pB[2*j2], pB[2*j2+1] }; PKFMA(pv[j2], w, ha); }
#pragma unroll
                for (int j2 = 0; j2 < 4; ++j2) { const v2f w = { pB[8 + 2*j2], pB[8 + 2*j2+1] }; PKFMA(pv[j2], w, hb2); }
                if (k2 + 1 < 16) S_WAIT1(pA);
            }
        }
    }

    // ---- alpha-head: serial scalar chain, k ascending (same as round 6) ----
    S_WAIT2(wA0, wA1);
    float s = b32[0];
#pragma unroll
    for (int k = 0; k < 16; ++k)
        s = fmaf((k & 1) ? a22[k >> 1].y : a22[k >> 1].x, wA0[k], s);
#pragma unroll
    for (int k = 16; k < 32; ++k)
        s = fmaf((k & 1) ? a22[k >> 1].y : a22[k >> 1].x, wA1[k - 16], s);
    const float alphax = 4.0f / (1.0f + __expf(-s));

    // ---- barrier terms ----
    float hx = 16.0f;
#pragma unroll
    for (int i = 0; i < NN; ++i) hx = fmaf(-x0[i], x0[i], hx);

    float dh[NN];
#pragma unroll
    for (int i = 0; i < NN; ++i) dh[i] = -2.0f * x0[i];

    float Lfhx = 0.0f;
#pragma unroll
    for (int i = 0; i < NN; ++i) {
        const float4 aq0 = *(const float4*)(Amat + i * NN);
        const float4 aq1 = *(const float4*)(Amat + i * NN + 4);
        float fx = 0.0f;
        fx = fmaf(aq0.x, x0[0], fx); fx = fmaf(aq0.y, x0[1], fx);
        fx = fmaf(aq0.z, x0[2], fx); fx = fmaf(aq0.w, x0[3], fx);
        fx = fmaf(aq1.x, x0[4], fx); fx = fmaf(aq1.y, x0[5], fx);
        fx = fmaf(aq1.z, x0[6], fx); fx = fmaf(aq1.w, x0[7], fx);
        Lfhx = fmaf(dh[i], fx, Lfhx);
    }

#define GDECL(j) float g##j = 0.0f;
    FOR8(GDECL)
#undef GDECL
#pragma unroll
    for (int i = 0; i < NN; ++i) {
        const float4 gq0 = *(const float4*)(Gmat + i * MM);
        const float4 gq1 = *(const float4*)(Gmat + i * MM + 4);
        const float da = dh[i];
        g0 = fmaf(da, gq0.x, g0); g1 = fmaf(da, gq0.y, g1);
        g2 = fmaf(da, gq0.z, g2); g3 = fmaf(da, gq0.w, g3);
        g4 = fmaf(da, gq1.x, g4); g5 = fmaf(da, gq1.y, g5);
        g6 = fmaf(da, gq1.z, g6); g7 = fmaf(da, gq1.w, g7);
    }

    const float c0 = fmaf(alphax, hx, Lfhx);

    // =====================================================================
    // QP via exact piecewise-linear root isolation — fully scalarized.
    // =====================================================================
#define DECL_PG(j) const float p##j = (j & 1) ? pv[j >> 1].y : pv[j >> 1].x;
    FOR8(DECL_PG)
#undef DECL_PG

    auto c_of = [&](float lam) -> float {
        float c = c0;
#define CTERM(j) { float u = fmaf(lam, g##j, -p##j);                  \
                   u = fminf(fmaxf(u, -1.0f), 1.0f);                  \
                   c = fmaf(g##j, u, c); }
        FOR8(CTERM)
#undef CTERM
        return c;
    };

    const bool viol = (c_of(0.0f) < 0.0f);

    const float BIGR = 3.0e38f;         // sentinel: no right bracket found
    float lamL = 0.0f, lamR = BIGR;
#define BP(j) {                                                        \
        const float rg = __builtin_amdgcn_rcpf(g##j);                  \
        const float bpa = (p##j - 1.0f) * rg;                          \
        const float bpb = (p##j + 1.0f) * rg;                          \
        const float ca = c_of(bpa);                                    \
        const float cb = c_of(bpb);                                    \
        lamL = (bpa > 0.0f && ca <  0.0f && bpa > lamL) ? bpa : lamL;  \
        lamR = (bpa > 0.0f && ca >= 0.0f && bpa < lamR) ? bpa : lamR;  \
        lamL = (bpb > 0.0f && cb <  0.0f && bpb > lamL) ? bpb : lamL;  \
        lamR = (bpb > 0.0f && cb >= 0.0f && bpb < lamR) ? bpb : lamR;  \
    }
    FOR8(BP)
#undef BP

    const bool infeas = (lamR == BIGR);
    float lam_t = infeas ? 1.099511627776e12f : 0.5f * (lamL + lamR);
    lam_t = viol ? lam_t : 0.0f;

    float denom = 0.0f, num = c0;
#define ASET(j)                                                        \
    const float ur##j = fmaf(lam_t, g##j, -p##j);                      \
    const bool lo##j = (ur##j <= -1.0f);                               \
    const bool hi##j = (ur##j >=  1.0f);                               \
    denom += (!(lo##j || hi##j)) ? g##j * g##j : 0.0f;                 \
    num   += lo##j ? -g##j : (hi##j ? g##j : -g##j * p##j);
    FOR8(ASET)
#undef ASET

    const float lam = viol ? (-num / (denom + 1e-12f)) : 0.0f;

#define UOUT(j) const float uo##j =                                    \
    lo##j ? -1.0f : (hi##j ? 1.0f : fmaf(lam, g##j, -p##j));
    FOR8(UOUT)
#undef UOUT

    float4* ov = reinterpret_cast<float4*>(out + (size_t)row * MM);
    ov[0] = make_float4(uo0, uo1, uo2, uo3);
    ov[1] = make_float4(uo4, uo5, uo6, uo7);
}

#define ARGS_DECL                                                       \
    const float* __restrict__ x_g,                                      \
    const float* __restrict__ W1,  const float* __restrict__ b1,        \
    const float* __restrict__ W21, const float* __restrict__ b21,       \
    const float* __restrict__ W22, const float* __restrict__ b22,       \
    const float* __restrict__ W31, const float* __restrict__ b31,       \
    const float* __restrict__ W32, const float* __restrict__ b32,       \
    const float* __restrict__ Amat, const float* __restrict__ Gmat,     \
    const float* __restrict__ mean, const float* __restrict__ std_,    \
    float* __restrict__ out
#define ARGS_PASS x_g, W1, b1, W21, b21, W22, b22, W31, b31, W32, b32, \
                  Amat, Gmat, mean, std_, out

__global__ __launch_bounds__(256, 2) void barrier_policy_clean(ARGS_DECL)
{
    const int row = blockIdx.x * 256 + threadIdx.x;
    compute_row(row, ARGS_PASS);
}

__global__ __launch_bounds__(256, 2) void barrier_policy_guard(ARGS_DECL, int B)
{
    const int row = blockIdx.x * 256 + threadIdx.x;
    if (row < B) compute_row(row, ARGS_PASS);
}

extern "C" void kernel_launch(void* const* d_in, const int* in_sizes, int n_in,
                              void* d_out, int out_size, void* d_ws, size_t ws_size,
                              hipStream_t stream) {
    const float* x    = (const float*)d_in[0];
    const float* W1   = (const float*)d_in[1];
    const float* b1   = (const float*)d_in[2];
    const float* W21  = (const float*)d_in[3];
    const float* b21  = (const float*)d_in[4];
    const float* W22  = (const float*)d_in[5];
    const float* b22  = (const float*)d_in[6];
    const float* W31  = (const float*)d_in[7];
    const float* b31  = (const float*)d_in[8];
    const float* W32  = (const float*)d_in[9];
    const float* b32  = (const float*)d_in[10];
    const float* Amat = (const float*)d_in[11];
    const float* Gmat = (const float*)d_in[12];
    const float* mean = (const float*)d_in[13];
    const float* std_ = (const float*)d_in[14];
    float* out = (float*)d_out;

    const int B = in_sizes[0] / NN;
    if (B % 256 == 0) {
        barrier_policy_clean<<<B / 256, 256, 0, stream>>>(
            x, W1, b1, W21, b21, W22, b22, W31, b31, W32, b32,
            Amat, Gmat, mean, std_, out);
    } else {
        barrier_policy_guard<<<(B + 255) / 256, 256, 0, stream>>>(
            x, W1, b1, W21, b21, W22, b22, W31, b31, W32, b32,
            Amat, Gmat, mean, std_, out, B);
    }
}